// Round 21
// baseline (193.668 us; speedup 1.0000x reference)
//
#include <hip/hip_runtime.h>

#define NUM_HEADS 16
#define HEAD_DIM  64
#define HIDDEN    1024
#define SEQ       512
#define BATCH     8
#define NBH       128      // BATCH*NUM_HEADS
#define POSN      512      // 2*BUCKET
#define SCALE_F   0.07216878364870323f   // 1/sqrt(3*HEAD_DIM)

typedef __attribute__((ext_vector_type(8))) short  short8;
typedef __attribute__((ext_vector_type(4))) short  short4_t;
typedef __attribute__((ext_vector_type(4))) float  floatx4;

// async global->LDS, 16B per lane (wave-uniform base + lane*16 dest --
// per-lane LDS addresses are IGNORED; dest chunk index MUST be lane-linear)
#define GLDS16(gsrc, ldst) \
    __builtin_amdgcn_global_load_lds((const __attribute__((address_space(1))) void*)(gsrc), \
                                     (__attribute__((address_space(3))) void*)(ldst), 16, 0, 0)

__device__ __forceinline__ float bits2f(short s) {
    union { unsigned u; float f; } x;
    x.u = ((unsigned)(unsigned short)s) << 16;
    return x.f;
}
__device__ __forceinline__ short f2bits(float f) {
    union { float f; unsigned u; } x;
    x.f = f;
    unsigned r = x.u + 0x7fffu + ((x.u >> 16) & 1u);
    return (short)(r >> 16);
}

// ---------------------------------------------------------------------------
// prep_all: conv_pair (blocks 0..4095), wtrans (4096..5119), ftab (5120..5123)
// ---------------------------------------------------------------------------
__global__ __launch_bounds__(256)
void prep_all(const float* __restrict__ a, const float* __restrict__ b,
              short* __restrict__ oa, short* __restrict__ ob,
              const float* __restrict__ w0, const float* __restrict__ w1,
              const float* __restrict__ w2, const float* __restrict__ w3,
              short* __restrict__ o0, short* __restrict__ o1,
              short* __restrict__ o2, short* __restrict__ o3,
              int* __restrict__ ftab)
{
    __shared__ float tile[64][65];
    const int bid = blockIdx.x, t = threadIdx.x;

    if (bid < 4096) {
        const int idx = bid * 256 + t;
        floatx4 va = ((const floatx4*)a)[idx];
        floatx4 vb = ((const floatx4*)b)[idx];
        short4_t ra, rb;
#pragma unroll
        for (int i = 0; i < 4; i++) { ra[i] = f2bits(va[i]); rb[i] = f2bits(vb[i]); }
        ((short4_t*)oa)[idx] = ra;
        ((short4_t*)ob)[idx] = rb;
        return;
    }
    if (bid < 5120) {
        const int r = bid - 4096;
        const int z = r >> 8, rem = r & 255;
        const float* src = (z == 0) ? w0 : (z == 1) ? w1 : (z == 2) ? w2 : w3;
        short*       dst = (z == 0) ? o0 : (z == 1) ? o1 : (z == 2) ? o2 : o3;
        const int c0 = (rem & 15) * 64, n0 = (rem >> 4) * 64;
#pragma unroll
        for (int j = 0; j < 16; j++) {
            const int e = t + j * 256;
            tile[e >> 6][e & 63] = src[(long)(c0 + (e >> 6)) * 1024 + n0 + (e & 63)];
        }
        __syncthreads();
#pragma unroll
        for (int j = 0; j < 16; j++) {
            const int e = t + j * 256;
            dst[(long)(n0 + (e >> 6)) * 1024 + c0 + (e & 63)] = f2bits(tile[e & 63][e >> 6]);
        }
        return;
    }
    const int i = (bid - 5120) * 256 + t;
    if (i >= 1023) return;
    const int delta = i - 511;
    const float Cf = (float)log(511.0 / 128.0);
    float absp = (delta < 128 && delta > -128) ? 127.0f : fabsf((float)delta);
    float bucket;
    if (absp <= 128.0f) {
        bucket = (float)delta;
    } else {
        float lp = ceilf((logf(absp * (1.0f / 128.0f)) * 127.0f) / Cf) + 128.0f;
        bucket = (delta > 0) ? lp : -lp;
    }
    int bi = (int)bucket + 256;
    bi = min(max(bi, 0), 511);
    ftab[i] = bi;
}

// ---------------------------------------------------------------------------
// gemm_nt: BK=64, 2-stage dbuf with COUNTED vmcnt (2 tiles in flight):
// prologue issues tiles 0,1; per iter: vmcnt(8) [oldest tile done] +
// s_barrier -> compute buf cur -> s_barrier -> issue tile i+2 into cur.
// Counter never drains to 0 mid-loop; loads get a full iteration to land.
// LDS 64 KB -> 2 blocks/CU. MODE 6: merged projections, grid (32, 40),
// XCD-chunked swizzle; V via LDS-transpose epilogue.
// ---------------------------------------------------------------------------
template<int MODE>
__global__ __launch_bounds__(256)
void gemm_nt(const short* __restrict__ A, long aBatch, int lda,
             const short* __restrict__ BT, long bBatch, int ldb,
             void* __restrict__ O0, void* __restrict__ O1, void* __restrict__ O2,
             long oBatch, int ldo,
             const float* __restrict__ b0, const float* __restrict__ b1,
             const float* __restrict__ b2, int Kd,
             const short* __restrict__ A2,
             void* __restrict__ O3, void* __restrict__ O4)
{
    __shared__ __align__(16) short As[2][128 * 64];
    __shared__ __align__(16) short Bs[2][128 * 64];

    int m0, n0, yy = 0;
    bool z1 = false;
    const int z = blockIdx.z;
    if (MODE == 6) {
        const int lin = blockIdx.x + (blockIdx.y << 5);      // 0..1279
        const int swz = (lin & 7) * 160 + (lin >> 3);        // XCD-chunked
        m0 = (swz & 31) * 128;
        yy = swz >> 5;                                        // 0..39
        z1 = (yy >= 24);
        n0 = (z1 ? (yy - 24) : yy) * 128;
    } else {
        m0 = blockIdx.x * 128;
        n0 = blockIdx.y * 128;
    }

    const short* Ab;
    const short* Bb;
    if (MODE == 6) {
        Ab = z1 ? A2 : A;
        Bb = BT;
    } else {
        Ab = A + (long)z * aBatch;
        Bb = BT + (long)z * bBatch;
    }

    const int t = threadIdx.x;
    const int l = t & 63, w = t >> 6;
    const int wm = w >> 1, wn = w & 1;
    const int lr = l & 15, lg = l >> 4;

    floatx4 acc[4][4];
#pragma unroll
    for (int i = 0; i < 4; i++)
#pragma unroll
        for (int j = 0; j < 4; j++) acc[i][j] = (floatx4){0.f, 0.f, 0.f, 0.f};

    const int niter = Kd >> 6;

    // prologue: stage tiles 0 and 1 (8 GLDS each)
#pragma unroll
    for (int j = 0; j < 4; j++) {
        const int c = (w * 4 + j) * 64 + l;   // 0..1023 (lane-linear dest)
        const int row = c >> 3, pc = c & 7;
        const int cc = pc ^ (row & 7);
        GLDS16(Ab + (long)(m0 + row) * lda + cc * 8, As[0] + c * 8);
        GLDS16(Bb + (long)(n0 + row) * ldb + cc * 8, Bs[0] + c * 8);
    }
    if (niter > 1) {
#pragma unroll
        for (int j = 0; j < 4; j++) {
            const int c = (w * 4 + j) * 64 + l;
            const int row = c >> 3, pc = c & 7;
            const int cc = pc ^ (row & 7);
            GLDS16(Ab + (long)(m0 + row) * lda + 64 + cc * 8, As[1] + c * 8);
            GLDS16(Bb + (long)(n0 + row) * ldb + 64 + cc * 8, Bs[1] + c * 8);
        }
    }

    int cur = 0;
    for (int i = 0; i < niter; i++, cur ^= 1) {
        __builtin_amdgcn_sched_barrier(0);
        if (i + 1 < niter) { asm volatile("s_waitcnt vmcnt(8)" ::: "memory"); }
        else               { asm volatile("s_waitcnt vmcnt(0)" ::: "memory"); }
        __builtin_amdgcn_s_barrier();
        __builtin_amdgcn_sched_barrier(0);
        // compute buf cur
#pragma unroll
        for (int ks = 0; ks < 2; ks++) {
            short8 af[4], bfr[4];
#pragma unroll
            for (int i4 = 0; i4 < 4; i4++) {
                const int mr = wm * 64 + i4 * 16 + lr;
                af[i4] = *(const short8*)((char*)As[cur] + mr * 128 + (((ks * 4 + lg) ^ (mr & 7)) * 16));
                const int nr = wn * 64 + i4 * 16 + lr;
                bfr[i4] = *(const short8*)((char*)Bs[cur] + nr * 128 + (((ks * 4 + lg) ^ (nr & 7)) * 16));
            }
#pragma unroll
            for (int i4 = 0; i4 < 4; i4++)
#pragma unroll
                for (int j4 = 0; j4 < 4; j4++)
                    acc[i4][j4] = __builtin_amdgcn_mfma_f32_16x16x32_bf16(af[i4], bfr[j4], acc[i4][j4], 0, 0, 0);
        }
        __builtin_amdgcn_sched_barrier(0);
        __builtin_amdgcn_s_barrier();   // all waves done reading buf cur
        __builtin_amdgcn_sched_barrier(0);
        if (i + 2 < niter) {
            const int kn = (i + 2) << 6;
#pragma unroll
            for (int j = 0; j < 4; j++) {
                const int c = (w * 4 + j) * 64 + l;
                const int row = c >> 3, pc = c & 7;
                const int cc = pc ^ (row & 7);
                GLDS16(Ab + (long)(m0 + row) * lda + kn + cc * 8, As[cur] + c * 8);
                GLDS16(Bb + (long)(n0 + row) * ldb + kn + cc * 8, Bs[cur] + c * 8);
            }
        }
    }
    __syncthreads();   // all waves done with LDS before epilogue reuse

    // ---- epilogue ----
    if (MODE == 6 && !z1 && yy >= 16) {
        // V quadrant: transpose via LDS (As[0]+As[1] = 32 KB), coalesced stores
        short* tp = &As[0][0];   // [128 rows ngl][128 cols ml], XOR-swizzled
#pragma unroll
        for (int i = 0; i < 4; i++)
#pragma unroll
            for (int j = 0; j < 4; j++)
#pragma unroll
                for (int e = 0; e < 4; e++) {
                    const int ml  = wm * 64 + i * 16 + lg * 4 + e;   // local m (=s)
                    const int ngl = wn * 64 + j * 16 + lr;           // local n
                    const float v = acc[i][j][e] + b2[(n0 & 1023) + ngl];
                    tp[ngl * 128 + (ml ^ ((ngl & 7) << 4))] = f2bits(v);
                }
        __syncthreads();
        const int b = m0 >> 9, s0 = m0 & 511;
        const int hb = (n0 & 1023) >> 6;
        short* dst = (short*)O2;
        // 2048 tasks: 128 rows x 16 chunks of 8 (full 128-wide s coverage)
#pragma unroll
        for (int j = 0; j < 8; j++) {
            const int task = t + j * 256;            // 0..2047
            const int r = task >> 4, c = task & 15;  // row ngl, 16B chunk
            short8 v8 = *(const short8*)(tp + r * 128 + ((c * 8) ^ ((r & 7) << 4)));
            const int h = hb + (r >> 6), d = r & 63;
            *(short8*)(dst + ((long)((b * NUM_HEADS + h) * HEAD_DIM + d)) * SEQ + s0 + c * 8) = v8;
        }
        return;
    }

#pragma unroll
    for (int i = 0; i < 4; i++) {
#pragma unroll
        for (int j = 0; j < 4; j++) {
#pragma unroll
            for (int e = 0; e < 4; e++) {
                const int mg = m0 + wm * 64 + i * 16 + lg * 4 + e;
                const int ng = n0 + wn * 64 + j * 16 + lr;
                float v = acc[i][j][e];
                if (MODE == 1) {
                    ((short*)O0)[(long)z * oBatch + (long)mg * ldo + ng] = f2bits(v);
                } else if (MODE == 2) {
                    ((float*)O0)[(long)mg * ldo + ng] = v + b0[ng];
                } else if (MODE == 6) {
                    const int hh = ng & 1023, mat = ng >> 10;
                    const int h = hh >> 6, d = hh & 63;
                    const int b = mg >> 9, s = mg & 511;
                    v += (mat == 0 ? b0 : b1)[hh];
                    short* dst;
                    if (z1) dst = (short*)(mat == 0 ? O3 : O4);
                    else    dst = (short*)(mat == 0 ? O0 : O1);
                    dst[((long)(b * NUM_HEADS + h) * SEQ + s) * HEAD_DIM + d] = f2bits(v);
                }
            }
        }
    }
}

// ---------------------------------------------------------------------------
// gemm_nt3: BK=32, 3-stage counted-vmcnt pipeline, LDS 48 KB -> 3 blocks/CU.
// Best for occupancy-starved small dispatches (c2p K=64, out-proj).
// Swizzle: slot = lg ^ ((row>>1)&3) (conflict-free for 64B rows).
// ---------------------------------------------------------------------------
template<int MODE>
__global__ __launch_bounds__(256)
void gemm_nt3(const short* __restrict__ A, long aBatch, int lda,
              const short* __restrict__ BT, long bBatch, int ldb,
              void* __restrict__ O0, long oBatch, int ldo,
              const float* __restrict__ b0, int Kd)
{
    __shared__ __align__(16) short LB[24576];

    const int z = blockIdx.z;
    const int m0 = blockIdx.x * 128, n0 = blockIdx.y * 128;
    const short* Ab = A + (long)z * aBatch;
    const short* Bb = BT + (long)z * bBatch;

    const int t = threadIdx.x;
    const int l = t & 63, w = t >> 6;
    const int wm = w >> 1, wn = w & 1;
    const int lr = l & 15, lg = l >> 4;

    const int c0c = t, c1c = t + 256;
    const int r0 = c0c >> 2, cc0 = (c0c & 3) ^ ((r0 >> 1) & 3);
    const int r1 = c1c >> 2, cc1 = (c1c & 3) ^ ((r1 >> 1) & 3);

    floatx4 acc[4][4];
#pragma unroll
    for (int i = 0; i < 4; i++)
#pragma unroll
        for (int j = 0; j < 4; j++) acc[i][j] = (floatx4){0.f, 0.f, 0.f, 0.f};

    const int niter = Kd >> 5;

    {
        GLDS16(Ab + (long)(m0 + r0) * lda + cc0 * 8, LB + c0c * 8);
        GLDS16(Ab + (long)(m0 + r1) * lda + cc1 * 8, LB + c1c * 8);
        GLDS16(Bb + (long)(n0 + r0) * ldb + cc0 * 8, LB + 12288 + c0c * 8);
        GLDS16(Bb + (long)(n0 + r1) * ldb + cc1 * 8, LB + 12288 + c1c * 8);
        GLDS16(Ab + (long)(m0 + r0) * lda + 32 + cc0 * 8, LB + 4096 + c0c * 8);
        GLDS16(Ab + (long)(m0 + r1) * lda + 32 + cc1 * 8, LB + 4096 + c1c * 8);
        GLDS16(Bb + (long)(n0 + r0) * ldb + 32 + cc0 * 8, LB + 12288 + 4096 + c0c * 8);
        GLDS16(Bb + (long)(n0 + r1) * ldb + 32 + cc1 * 8, LB + 12288 + 4096 + c1c * 8);
    }

    int cbase = 0;
    int ibase = 8192;
    for (int i = 0; i < niter; i++) {
        __builtin_amdgcn_sched_barrier(0);
        if (i + 1 < niter) { asm volatile("s_waitcnt vmcnt(4)" ::: "memory"); }
        else               { asm volatile("s_waitcnt vmcnt(0)" ::: "memory"); }
        __builtin_amdgcn_s_barrier();
        __builtin_amdgcn_sched_barrier(0);
        if (i + 2 < niter) {
            const int kn = (i + 2) << 5;
            GLDS16(Ab + (long)(m0 + r0) * lda + kn + cc0 * 8, LB + ibase + c0c * 8);
            GLDS16(Ab + (long)(m0 + r1) * lda + kn + cc1 * 8, LB + ibase + c1c * 8);
            GLDS16(Bb + (long)(n0 + r0) * ldb + kn + cc0 * 8, LB + 12288 + ibase + c0c * 8);
            GLDS16(Bb + (long)(n0 + r1) * ldb + kn + cc1 * 8, LB + 12288 + ibase + c1c * 8);
        }
        const short* Asb = LB + cbase;
        const short* Bsb = LB + 12288 + cbase;
        short8 af[4], bfr[4];
#pragma unroll
        for (int i4 = 0; i4 < 4; i4++) {
            const int mr = wm * 64 + i4 * 16 + lr;
            af[i4] = *(const short8*)((const char*)Asb + mr * 64 + ((lg ^ ((mr >> 1) & 3)) * 16));
            const int nr = wn * 64 + i4 * 16 + lr;
            bfr[i4] = *(const short8*)((const char*)Bsb + nr * 64 + ((lg ^ ((nr >> 1) & 3)) * 16));
        }
#pragma unroll
        for (int i4 = 0; i4 < 4; i4++)
#pragma unroll
            for (int j4 = 0; j4 < 4; j4++)
                acc[i4][j4] = __builtin_amdgcn_mfma_f32_16x16x32_bf16(af[i4], bfr[j4], acc[i4][j4], 0, 0, 0);
        cbase += 4096; if (cbase == 12288) cbase = 0;
        ibase += 4096; if (ibase == 12288) ibase = 0;
    }

#pragma unroll
    for (int i = 0; i < 4; i++) {
#pragma unroll
        for (int j = 0; j < 4; j++) {
#pragma unroll
            for (int e = 0; e < 4; e++) {
                const int mg = m0 + wm * 64 + i * 16 + lg * 4 + e;
                const int ng = n0 + wn * 64 + j * 16 + lr;
                float v = acc[i][j][e];
                if (MODE == 1) {
                    ((short*)O0)[(long)z * oBatch + (long)mg * ldo + ng] = f2bits(v);
                } else {
                    ((float*)O0)[(long)mg * ldo + ng] = v + b0[ng];
                }
            }
        }
    }
}

// ---------------------------------------------------------------------------
// p2c_fused: per (k-octant of 64, bh) block (512 threads, 8 waves).
// XCD-chunked grid: each XCD owns 16 complete bh -> c2p/posQ/K L2-local.
//   strip[p][kk] = sum_d posQ[p][d] * K[k0+kk][d]   (512 x 64, MFMA)
//   then combined bias plane in fragment-packed layout.
// ---------------------------------------------------------------------------
__global__ __launch_bounds__(512, 2)
void p2c_fused(const short* __restrict__ posQ, const short* __restrict__ K,
               const short* __restrict__ c2pf, const int* __restrict__ ftab,
               short* __restrict__ Bias)
{
    __shared__ __align__(16) short As[512 * 64];   // posQ staged; later strip
    __shared__ __align__(16) short Bs[64 * 64];    // K slice
    __shared__ short ft[1024];
    const int lin = blockIdx.x;
    const int swz = (lin & 7) * 128 + (lin >> 3);
    const int bh = swz >> 3, ko = swz & 7;
    const int k0 = ko * 64;
    const int t = threadIdx.x, l = t & 63, w = t >> 6;
    const int lr = l & 15, lg = l >> 4;
    const short* Ab = posQ + (long)bh * SEQ * HEAD_DIM;
    const short* Kb = K + (long)bh * SEQ * HEAD_DIM;
    const short* c2pb = c2pf + (long)bh * SEQ * POSN;

    for (int i = t; i < 1024; i += 512) ft[i] = (short)((i < 1023) ? ftab[i] : 0);

#pragma unroll
    for (int j = 0; j < 8; j++) {
        const int c = j * 512 + t;            // 0..4095 (lane-linear dest)
        const int row = c >> 3, pc = c & 7;
        const int cc = pc ^ (row & 7);
        GLDS16(Ab + (long)row * HEAD_DIM + cc * 8, As + c * 8);
    }
    {
        const int c = t;                      // 0..511
        const int row = c >> 3, pc = c & 7;
        const int cc = pc ^ (row & 7);
        GLDS16(Kb + (long)(k0 + row) * HEAD_DIM + cc * 8, Bs + c * 8);
    }
    __syncthreads();

    floatx4 acc[4][4];
#pragma unroll
    for (int i = 0; i < 4; i++)
#pragma unroll
        for (int j = 0; j < 4; j++) acc[i][j] = (floatx4){0.f, 0.f, 0.f, 0.f};
#pragma unroll
    for (int ks = 0; ks < 2; ks++) {
        short8 af[4], bfr[4];
#pragma unroll
        for (int i = 0; i < 4; i++) {
            const int mr = w * 64 + i * 16 + lr;
            af[i] = *(const short8*)((char*)As + mr * 128 + (((ks * 4 + lg) ^ (mr & 7)) * 16));
            const int nr = i * 16 + lr;
            bfr[i] = *(const short8*)((char*)Bs + nr * 128 + (((ks * 4 + lg) ^ (nr & 7)) * 16));
        }
#pragma unroll
        for (int i = 0; i < 4; i++)
#pragma unroll
            for (int j = 0; j < 4; j++)
                acc[i][j] = __builtin_amdgcn_mfma_f32_16x16x32_bf16(af[i], bfr[j], acc[i][j], 0, 0, 0);
    }
    __syncthreads();   // all As/Bs reads done -> reuse As as strip

#pragma unroll
    for (int i = 0; i < 4; i++)
#pragma unroll
        for (int j = 0; j < 4; j++)
#pragma unroll
            for (int e = 0; e < 4; e++) {
                const int p = w * 64 + i * 16 + lg * 4 + e;
                const int kk = j * 16 + lr;
                As[p * 64 + (kk ^ (lg << 4))] = f2bits(acc[i][j][e]);
            }
    __syncthreads();

    // combined-bias build: 4096 tasks, fragment-packed stores
    short* Bb = Bias + (long)bh * SEQ * SEQ;    // [16 qt][16384]
#pragma unroll
    for (int j = 0; j < 8; j++) {
        const int task = j * 512 + t;
        const int qt = task >> 8;              // 0..15
        const int kl = (task >> 2) & 63;       // 0..63
        const int rc = task & 3;               // 0..3
        const int k  = k0 + kl;
        short8 v;
#pragma unroll
        for (int i = 0; i < 8; i++) {
            const int q  = qt * 32 + rc * 8 + i;
            const int fk = (int)ft[q - k + 511];
            const float sv = bits2f(As[fk * 64 + (kl ^ (((fk >> 2) & 3) << 4))]);
            const float cv = bits2f(c2pb[(long)q * POSN + fk]);
            v[i] = f2bits(sv + cv);
        }
        short* Bq = Bb + qt * 16384;
        const int mt  = rc >> 1;
        const int lg0 = (rc * 2) & 3;
        const int pb  = (((mt * 4 + (k >> 7)) * 8 + ((k >> 4) & 7)) * 64
                         + (lg0 * 16 + (k & 15))) * 4;
        *(short4_t*)(Bq + pb)      = (short4_t){v[0], v[1], v[2], v[3]};
        *(short4_t*)(Bq + pb + 64) = (short4_t){v[4], v[5], v[6], v[7]};
    }
}

// ---------------------------------------------------------------------------
// Fused attention per (b,h, 32-row q-tile). 4 waves, ONE barrier.
//   Fragment-packed bias -> 16 coalesced short4 loads; no-max softmax;
//   fused exp+sum+P-write; setprio around MFMA clusters.
// LDS 32.5 KB -> 4 blocks/CU.
// ---------------------------------------------------------------------------
__global__ __launch_bounds__(256, 4)
void attn_fused(const short* __restrict__ Q, const short* __restrict__ K,
                const short* __restrict__ Vt, const short* __restrict__ Bias,
                short* __restrict__ attnO)
{
    __shared__ __align__(16) short PS[32 * 512];   // swizzled P tile
    __shared__ float red[4][32];                   // wave-partial row sums

    const int lin  = blockIdx.x;
    const int lin2 = (lin & 7) * 256 + (lin >> 3);
    const int bh = lin2 >> 4, qt = lin2 & 15;
    const int q0 = qt * 32;
    const int t = threadIdx.x, l = t & 63, w = t >> 6;
    const int lr = l & 15, lg = l >> 4;
    const long pbase = (long)bh * SEQ * HEAD_DIM;
    const short* Qb  = Q  + pbase;
    const short* Kb  = K  + pbase;
    const short* Vtb = Vt + pbase;
    const short* Bb  = Bias + ((long)bh * 16 + qt) * (512 * 32);

    short4_t bfrag[2][8];
#pragma unroll
    for (int mt = 0; mt < 2; mt++)
#pragma unroll
        for (int nt = 0; nt < 8; nt++)
            bfrag[mt][nt] = *(const short4_t*)(Bb + ((((mt * 4 + w) * 8 + nt) * 64 + l) << 2));

    short8 aq[2][2];
#pragma unroll
    for (int mt = 0; mt < 2; mt++)
#pragma unroll
        for (int ks = 0; ks < 2; ks++)
            aq[mt][ks] = *(const short8*)(Qb + (q0 + mt * 16 + lr) * 64 + ks * 32 + lg * 8);

    floatx4 acc[2][8];
#pragma unroll
    for (int mt = 0; mt < 2; mt++)
#pragma unroll
        for (int nt = 0; nt < 8; nt++) acc[mt][nt] = (floatx4){0.f, 0.f, 0.f, 0.f};

    __builtin_amdgcn_s_setprio(1);
#pragma unroll
    for (int nt = 0; nt < 8; nt++) {
        const int kr = w * 128 + nt * 16 + lr;
        short8 kb0 = *(const short8*)(Kb + kr * 64 + lg * 8);
        short8 kb1 = *(const short8*)(Kb + kr * 64 + 32 + lg * 8);
#pragma unroll
        for (int mt = 0; mt < 2; mt++) {
            acc[mt][nt] = __builtin_amdgcn_mfma_f32_16x16x32_bf16(aq[mt][0], kb0, acc[mt][nt], 0, 0, 0);
            acc[mt][nt] = __builtin_amdgcn_mfma_f32_16x16x32_bf16(aq[mt][1], kb1, acc[mt][nt], 0, 0, 0);
        }
    }
    __builtin_amdgcn_s_setprio(0);

#pragma unroll
    for (int mt = 0; mt < 2; mt++)
#pragma unroll
        for (int e = 0; e < 4; e++) {
            const int r = mt * 16 + lg * 4 + e;
            float s = 0.f;
#pragma unroll
            for (int nt = 0; nt < 8; nt++) {
                float p = __expf((acc[mt][nt][e] + bits2f(bfrag[mt][nt][e])) * SCALE_F);
                acc[mt][nt][e] = p;
                s += p;
            }
            s += __shfl_xor(s, 1); s += __shfl_xor(s, 2);
            s += __shfl_xor(s, 4); s += __shfl_xor(s, 8);
            red[w][r] = s;
#pragma unroll
            for (int nt = 0; nt < 8; nt++) {
                const int kcol = w * 128 + nt * 16 + lr;
                int byte = r * 1024 + kcol * 2;
                byte ^= (r & 7) << 4;
                *(short*)((char*)PS + byte) = f2bits(acc[mt][nt][e]);
            }
        }
    __syncthreads();   // P tile + partial sums visible

    floatx4 accO[2];
    accO[0] = (floatx4){0.f, 0.f, 0.f, 0.f};
    accO[1] = (floatx4){0.f, 0.f, 0.f, 0.f};
    __builtin_amdgcn_s_setprio(1);
#pragma unroll
    for (int ks = 0; ks < 16; ks++) {
        short8 vb = *(const short8*)(Vtb + (long)(w * 16 + lr) * SEQ + ks * 32 + lg * 8);
#pragma unroll
        for (int mt = 0; mt < 2; mt++) {
            const int qr = mt * 16 + lr;
            int byte = qr * 1024 + (ks * 32 + lg * 8) * 2;
            byte ^= (qr & 7) << 4;
            short8 pa = *(const short8*)((char*)PS + byte);
            accO[mt] = __builtin_amdgcn_mfma_f32_16x16x32_bf16(pa, vb, accO[mt], 0, 0, 0);
        }
    }
    __builtin_amdgcn_s_setprio(0);

    const int b = bh >> 4, h = bh & 15;
#pragma unroll
    for (int mt = 0; mt < 2; mt++)
#pragma unroll
        for (int e = 0; e < 4; e++) {
            const int r = mt * 16 + lg * 4 + e;
            const float rs = red[0][r] + red[1][r] + red[2][r] + red[3][r];
            const float v = accO[mt][e] / rs;
            attnO[((long)(b * SEQ + q0 + r)) * HIDDEN + h * HEAD_DIM + w * 16 + lr] = f2bits(v);
        }
}

// ---------------------------------------------------------------------------
extern "C" void kernel_launch(void* const* d_in, const int* in_sizes, int n_in,
                              void* d_out, int out_size, void* d_ws, size_t ws_size,
                              hipStream_t stream)
{
    const float* inputs = (const float*)d_in[0];
    const float* rel    = (const float*)d_in[1];
    const float* Wq     = (const float*)d_in[2];
    const float* bq     = (const float*)d_in[3];
    const float* Wk     = (const float*)d_in[4];
    const float* bk     = (const float*)d_in[5];
    const float* Wv     = (const float*)d_in[6];
    const float* bv     = (const float*)d_in[7];
    const float* Wo     = (const float*)d_in[8];
    const float* bo     = (const float*)d_in[9];
    float* out = (float*)d_out;

    char* ws = (char*)d_ws;
    size_t off = 0;
    auto alloc = [&](size_t bytes) -> char* {
        char* p = ws + off;
        off += (bytes + 255) & ~(size_t)255;
        return p;
    };
    short* inA   = (short*)alloc(4194304ull * 2);
    short* inRel = (short*)alloc(4194304ull * 2);
    short* WqT   = (short*)alloc(1048576ull * 2);   // WqT/WkT/WvT contiguous ->
    short* WkT   = (short*)alloc(1048576ull * 2);   // concat B for fused GEMMs
    short* WvT   = (short*)alloc(1048576ull * 2);
    short* WoT   = (short*)alloc(1048576ull * 2);
    short* Qw    = (short*)alloc(4194304ull * 2);
    short* Kw    = (short*)alloc(4194304ull * 2);
    short* Vtw   = (short*)alloc(4194304ull * 2);
    short* posQw = (short*)alloc(4194304ull * 2);
    short* posKw = (short*)alloc(4194304ull * 2);
    short* c2pW  = (short*)alloc(33554432ull * 2);
    short* BW    = (short*)alloc(33554432ull * 2);  // combined pos-bias plane
    short* attnW = (short*)alloc(4194304ull * 2);
    int*   ftabW = (int*)alloc(4096);
    // total ws: ~209.7 MB (known-safe footprint)

    // prep (conv + wtrans + ftab in one launch)
    prep_all<<<5124, 256, 0, stream>>>(inputs, rel, inA, inRel,
                                       Wq, Wk, Wv, Wo, WqT, WkT, WvT, WoT, ftabW);

    // merged projections (BK=64 counted-vmcnt 2-stage)
    gemm_nt<6><<<dim3(32, 40), 256, 0, stream>>>(inA, 0, 1024, WqT, 0, 1024,
                                                 Qw, Kw, Vtw, 0, 0, bq, bk, bv, 1024,
                                                 inRel, posQw, posKw);

    // c2p score GEMM: c2p = Q @ posK^T  (3-stage variant — best occupancy)
    gemm_nt3<1><<<dim3(4, 4, 128), 256, 0, stream>>>(Qw, 32768, 64, posKw, 32768, 64,
                                                     c2pW, 262144, 512, nullptr, 64);

    // p2c strip GEMM + c2p gather + combine -> fragment-packed Bias
    p2c_fused<<<1024, 512, 0, stream>>>(posQw, Kw, c2pW, ftabW, BW);

    // fused scores+softmax+PV (q-tile 32, one barrier, no-max softmax)
    attn_fused<<<2048, 256, 0, stream>>>(Qw, Kw, Vtw, BW, attnW);

    // output projection (3-stage variant)
    gemm_nt3<2><<<dim3(32, 8), 256, 0, stream>>>(attnW, 0, 1024, WoT, 0, 1024,
                                                 out, 0, 1024, bo, 1024);
}

// Round 22
// 188.604 us; speedup vs baseline: 1.0269x; 1.0269x over previous
//
#include <hip/hip_runtime.h>

#define NUM_HEADS 16
#define HEAD_DIM  64
#define HIDDEN    1024
#define SEQ       512
#define BATCH     8
#define NBH       128      // BATCH*NUM_HEADS
#define POSN      512      // 2*BUCKET
#define SCALE_F   0.07216878364870323f   // 1/sqrt(3*HEAD_DIM)

typedef __attribute__((ext_vector_type(8))) short  short8;
typedef __attribute__((ext_vector_type(4))) short  short4_t;
typedef __attribute__((ext_vector_type(4))) float  floatx4;

// async global->LDS, 16B per lane (wave-uniform base + lane*16 dest --
// per-lane LDS addresses are IGNORED; dest chunk index MUST be lane-linear)
#define GLDS16(gsrc, ldst) \
    __builtin_amdgcn_global_load_lds((const __attribute__((address_space(1))) void*)(gsrc), \
                                     (__attribute__((address_space(3))) void*)(ldst), 16, 0, 0)

__device__ __forceinline__ float bits2f(short s) {
    union { unsigned u; float f; } x;
    x.u = ((unsigned)(unsigned short)s) << 16;
    return x.f;
}
__device__ __forceinline__ short f2bits(float f) {
    union { float f; unsigned u; } x;
    x.f = f;
    unsigned r = x.u + 0x7fffu + ((x.u >> 16) & 1u);
    return (short)(r >> 16);
}

// ---------------------------------------------------------------------------
// prep_all: conv_pair (blocks 0..4095), wtrans (4096..5119), ftab (5120..5123)
// ---------------------------------------------------------------------------
__global__ __launch_bounds__(256)
void prep_all(const float* __restrict__ a, const float* __restrict__ b,
              short* __restrict__ oa, short* __restrict__ ob,
              const float* __restrict__ w0, const float* __restrict__ w1,
              const float* __restrict__ w2, const float* __restrict__ w3,
              short* __restrict__ o0, short* __restrict__ o1,
              short* __restrict__ o2, short* __restrict__ o3,
              int* __restrict__ ftab)
{
    __shared__ float tile[64][65];
    const int bid = blockIdx.x, t = threadIdx.x;

    if (bid < 4096) {
        const int idx = bid * 256 + t;
        floatx4 va = ((const floatx4*)a)[idx];
        floatx4 vb = ((const floatx4*)b)[idx];
        short4_t ra, rb;
#pragma unroll
        for (int i = 0; i < 4; i++) { ra[i] = f2bits(va[i]); rb[i] = f2bits(vb[i]); }
        ((short4_t*)oa)[idx] = ra;
        ((short4_t*)ob)[idx] = rb;
        return;
    }
    if (bid < 5120) {
        const int r = bid - 4096;
        const int z = r >> 8, rem = r & 255;
        const float* src = (z == 0) ? w0 : (z == 1) ? w1 : (z == 2) ? w2 : w3;
        short*       dst = (z == 0) ? o0 : (z == 1) ? o1 : (z == 2) ? o2 : o3;
        const int c0 = (rem & 15) * 64, n0 = (rem >> 4) * 64;
#pragma unroll
        for (int j = 0; j < 16; j++) {
            const int e = t + j * 256;
            tile[e >> 6][e & 63] = src[(long)(c0 + (e >> 6)) * 1024 + n0 + (e & 63)];
        }
        __syncthreads();
#pragma unroll
        for (int j = 0; j < 16; j++) {
            const int e = t + j * 256;
            dst[(long)(n0 + (e >> 6)) * 1024 + c0 + (e & 63)] = f2bits(tile[e & 63][e >> 6]);
        }
        return;
    }
    const int i = (bid - 5120) * 256 + t;
    if (i >= 1023) return;
    const int delta = i - 511;
    const float Cf = (float)log(511.0 / 128.0);
    float absp = (delta < 128 && delta > -128) ? 127.0f : fabsf((float)delta);
    float bucket;
    if (absp <= 128.0f) {
        bucket = (float)delta;
    } else {
        float lp = ceilf((logf(absp * (1.0f / 128.0f)) * 127.0f) / Cf) + 128.0f;
        bucket = (delta > 0) ? lp : -lp;
    }
    int bi = (int)bucket + 256;
    bi = min(max(bi, 0), 511);
    ftab[i] = bi;
}

// ---------------------------------------------------------------------------
// gemm_nt: BK=64, 2-stage double-buffer, one barrier/iter (best for K=1024;
// measured 56.4us vs 62-65 for deeper pipelines -- minimum synchronization
// wins at this tile size). LDS 64 KB -> 2 blocks/CU. MODE 6: merged
// projections, grid (32, 40), XCD-chunked swizzle; V via LDS-transpose.
// ---------------------------------------------------------------------------
template<int MODE>
__global__ __launch_bounds__(256)
void gemm_nt(const short* __restrict__ A, long aBatch, int lda,
             const short* __restrict__ BT, long bBatch, int ldb,
             void* __restrict__ O0, void* __restrict__ O1, void* __restrict__ O2,
             long oBatch, int ldo,
             const float* __restrict__ b0, const float* __restrict__ b1,
             const float* __restrict__ b2, int Kd,
             const short* __restrict__ A2,
             void* __restrict__ O3, void* __restrict__ O4)
{
    __shared__ __align__(16) short As[2][128 * 64];
    __shared__ __align__(16) short Bs[2][128 * 64];

    int m0, n0, yy = 0;
    bool z1 = false;
    const int z = blockIdx.z;
    if (MODE == 6) {
        const int lin = blockIdx.x + (blockIdx.y << 5);      // 0..1279
        const int swz = (lin & 7) * 160 + (lin >> 3);        // XCD-chunked
        m0 = (swz & 31) * 128;
        yy = swz >> 5;                                        // 0..39
        z1 = (yy >= 24);
        n0 = (z1 ? (yy - 24) : yy) * 128;
    } else {
        m0 = blockIdx.x * 128;
        n0 = blockIdx.y * 128;
    }

    const short* Ab;
    const short* Bb;
    if (MODE == 6) {
        Ab = z1 ? A2 : A;
        Bb = BT;
    } else {
        Ab = A + (long)z * aBatch;
        Bb = BT + (long)z * bBatch;
    }

    const int t = threadIdx.x;
    const int l = t & 63, w = t >> 6;
    const int wm = w >> 1, wn = w & 1;
    const int lr = l & 15, lg = l >> 4;

    floatx4 acc[4][4];
#pragma unroll
    for (int i = 0; i < 4; i++)
#pragma unroll
        for (int j = 0; j < 4; j++) acc[i][j] = (floatx4){0.f, 0.f, 0.f, 0.f};

    // prologue: stage tile 0 into buffer 0
#pragma unroll
    for (int j = 0; j < 4; j++) {
        const int c = (w * 4 + j) * 64 + l;   // 0..1023 (lane-linear dest)
        const int row = c >> 3, pc = c & 7;
        const int cc = pc ^ (row & 7);
        GLDS16(Ab + (long)(m0 + row) * lda + cc * 8, As[0] + c * 8);
        GLDS16(Bb + (long)(n0 + row) * ldb + cc * 8, Bs[0] + c * 8);
    }
    __syncthreads();   // vmcnt drain + barrier: buffer 0 ready

    int cur = 0;
    for (int k0 = 0; k0 < Kd; k0 += 64, cur ^= 1) {
        if (k0 + 64 < Kd) {
            const int kn = k0 + 64;
#pragma unroll
            for (int j = 0; j < 4; j++) {
                const int c = (w * 4 + j) * 64 + l;
                const int row = c >> 3, pc = c & 7;
                const int cc = pc ^ (row & 7);
                GLDS16(Ab + (long)(m0 + row) * lda + kn + cc * 8, As[cur ^ 1] + c * 8);
                GLDS16(Bb + (long)(n0 + row) * ldb + kn + cc * 8, Bs[cur ^ 1] + c * 8);
            }
        }
#pragma unroll
        for (int ks = 0; ks < 2; ks++) {
            short8 af[4], bfr[4];
#pragma unroll
            for (int i = 0; i < 4; i++) {
                const int mr = wm * 64 + i * 16 + lr;
                af[i] = *(const short8*)((char*)As[cur] + mr * 128 + (((ks * 4 + lg) ^ (mr & 7)) * 16));
                const int nr = wn * 64 + i * 16 + lr;
                bfr[i] = *(const short8*)((char*)Bs[cur] + nr * 128 + (((ks * 4 + lg) ^ (nr & 7)) * 16));
            }
#pragma unroll
            for (int i = 0; i < 4; i++)
#pragma unroll
                for (int j = 0; j < 4; j++)
                    acc[i][j] = __builtin_amdgcn_mfma_f32_16x16x32_bf16(af[i], bfr[j], acc[i][j], 0, 0, 0);
        }
        __syncthreads();   // all reads of cur done; next buffer's loads drained
    }

    // ---- epilogue ----
    if (MODE == 6 && !z1 && yy >= 16) {
        // V quadrant: transpose via LDS (As[0]+As[1] = 32 KB), coalesced stores
        short* tp = &As[0][0];   // [128 rows ngl][128 cols ml], XOR-swizzled
#pragma unroll
        for (int i = 0; i < 4; i++)
#pragma unroll
            for (int j = 0; j < 4; j++)
#pragma unroll
                for (int e = 0; e < 4; e++) {
                    const int ml  = wm * 64 + i * 16 + lg * 4 + e;   // local m (=s)
                    const int ngl = wn * 64 + j * 16 + lr;           // local n
                    const float v = acc[i][j][e] + b2[(n0 & 1023) + ngl];
                    tp[ngl * 128 + (ml ^ ((ngl & 7) << 4))] = f2bits(v);
                }
        __syncthreads();
        const int b = m0 >> 9, s0 = m0 & 511;
        const int hb = (n0 & 1023) >> 6;
        short* dst = (short*)O2;
        // 2048 tasks: 128 rows x 16 chunks of 8 (full 128-wide s coverage)
#pragma unroll
        for (int j = 0; j < 8; j++) {
            const int task = t + j * 256;            // 0..2047
            const int r = task >> 4, c = task & 15;  // row ngl, 16B chunk
            short8 v8 = *(const short8*)(tp + r * 128 + ((c * 8) ^ ((r & 7) << 4)));
            const int h = hb + (r >> 6), d = r & 63;
            *(short8*)(dst + ((long)((b * NUM_HEADS + h) * HEAD_DIM + d)) * SEQ + s0 + c * 8) = v8;
        }
        return;
    }

#pragma unroll
    for (int i = 0; i < 4; i++) {
#pragma unroll
        for (int j = 0; j < 4; j++) {
#pragma unroll
            for (int e = 0; e < 4; e++) {
                const int mg = m0 + wm * 64 + i * 16 + lg * 4 + e;
                const int ng = n0 + wn * 64 + j * 16 + lr;
                float v = acc[i][j][e];
                if (MODE == 1) {
                    ((short*)O0)[(long)z * oBatch + (long)mg * ldo + ng] = f2bits(v);
                } else if (MODE == 2) {
                    ((float*)O0)[(long)mg * ldo + ng] = v + b0[ng];
                } else if (MODE == 6) {
                    const int hh = ng & 1023, mat = ng >> 10;
                    const int h = hh >> 6, d = hh & 63;
                    const int b = mg >> 9, s = mg & 511;
                    v += (mat == 0 ? b0 : b1)[hh];
                    short* dst;
                    if (z1) dst = (short*)(mat == 0 ? O3 : O4);
                    else    dst = (short*)(mat == 0 ? O0 : O1);
                    dst[((long)(b * NUM_HEADS + h) * SEQ + s) * HEAD_DIM + d] = f2bits(v);
                }
            }
        }
    }
}

// ---------------------------------------------------------------------------
// gemm_nt3: BK=32, 3-stage counted-vmcnt pipeline, LDS 48 KB -> 3 blocks/CU.
// Best for occupancy-starved small dispatches (c2p K=64, out-proj).
// Swizzle: slot = lg ^ ((row>>1)&3) (conflict-free for 64B rows).
// ---------------------------------------------------------------------------
template<int MODE>
__global__ __launch_bounds__(256)
void gemm_nt3(const short* __restrict__ A, long aBatch, int lda,
              const short* __restrict__ BT, long bBatch, int ldb,
              void* __restrict__ O0, long oBatch, int ldo,
              const float* __restrict__ b0, int Kd)
{
    __shared__ __align__(16) short LB[24576];

    const int z = blockIdx.z;
    const int m0 = blockIdx.x * 128, n0 = blockIdx.y * 128;
    const short* Ab = A + (long)z * aBatch;
    const short* Bb = BT + (long)z * bBatch;

    const int t = threadIdx.x;
    const int l = t & 63, w = t >> 6;
    const int wm = w >> 1, wn = w & 1;
    const int lr = l & 15, lg = l >> 4;

    const int c0c = t, c1c = t + 256;
    const int r0 = c0c >> 2, cc0 = (c0c & 3) ^ ((r0 >> 1) & 3);
    const int r1 = c1c >> 2, cc1 = (c1c & 3) ^ ((r1 >> 1) & 3);

    floatx4 acc[4][4];
#pragma unroll
    for (int i = 0; i < 4; i++)
#pragma unroll
        for (int j = 0; j < 4; j++) acc[i][j] = (floatx4){0.f, 0.f, 0.f, 0.f};

    const int niter = Kd >> 5;

    {
        GLDS16(Ab + (long)(m0 + r0) * lda + cc0 * 8, LB + c0c * 8);
        GLDS16(Ab + (long)(m0 + r1) * lda + cc1 * 8, LB + c1c * 8);
        GLDS16(Bb + (long)(n0 + r0) * ldb + cc0 * 8, LB + 12288 + c0c * 8);
        GLDS16(Bb + (long)(n0 + r1) * ldb + cc1 * 8, LB + 12288 + c1c * 8);
        GLDS16(Ab + (long)(m0 + r0) * lda + 32 + cc0 * 8, LB + 4096 + c0c * 8);
        GLDS16(Ab + (long)(m0 + r1) * lda + 32 + cc1 * 8, LB + 4096 + c1c * 8);
        GLDS16(Bb + (long)(n0 + r0) * ldb + 32 + cc0 * 8, LB + 12288 + 4096 + c0c * 8);
        GLDS16(Bb + (long)(n0 + r1) * ldb + 32 + cc1 * 8, LB + 12288 + 4096 + c1c * 8);
    }

    int cbase = 0;
    int ibase = 8192;
    for (int i = 0; i < niter; i++) {
        __builtin_amdgcn_sched_barrier(0);
        if (i + 1 < niter) { asm volatile("s_waitcnt vmcnt(4)" ::: "memory"); }
        else               { asm volatile("s_waitcnt vmcnt(0)" ::: "memory"); }
        __builtin_amdgcn_s_barrier();
        __builtin_amdgcn_sched_barrier(0);
        if (i + 2 < niter) {
            const int kn = (i + 2) << 5;
            GLDS16(Ab + (long)(m0 + r0) * lda + kn + cc0 * 8, LB + ibase + c0c * 8);
            GLDS16(Ab + (long)(m0 + r1) * lda + kn + cc1 * 8, LB + ibase + c1c * 8);
            GLDS16(Bb + (long)(n0 + r0) * ldb + kn + cc0 * 8, LB + 12288 + ibase + c0c * 8);
            GLDS16(Bb + (long)(n0 + r1) * ldb + kn + cc1 * 8, LB + 12288 + ibase + c1c * 8);
        }
        const short* Asb = LB + cbase;
        const short* Bsb = LB + 12288 + cbase;
        short8 af[4], bfr[4];
#pragma unroll
        for (int i4 = 0; i4 < 4; i4++) {
            const int mr = wm * 64 + i4 * 16 + lr;
            af[i4] = *(const short8*)((const char*)Asb + mr * 64 + ((lg ^ ((mr >> 1) & 3)) * 16));
            const int nr = wn * 64 + i4 * 16 + lr;
            bfr[i4] = *(const short8*)((const char*)Bsb + nr * 64 + ((lg ^ ((nr >> 1) & 3)) * 16));
        }
#pragma unroll
        for (int i4 = 0; i4 < 4; i4++)
#pragma unroll
            for (int j4 = 0; j4 < 4; j4++)
                acc[i4][j4] = __builtin_amdgcn_mfma_f32_16x16x32_bf16(af[i4], bfr[j4], acc[i4][j4], 0, 0, 0);
        cbase += 4096; if (cbase == 12288) cbase = 0;
        ibase += 4096; if (ibase == 12288) ibase = 0;
    }

#pragma unroll
    for (int i = 0; i < 4; i++) {
#pragma unroll
        for (int j = 0; j < 4; j++) {
#pragma unroll
            for (int e = 0; e < 4; e++) {
                const int mg = m0 + wm * 64 + i * 16 + lg * 4 + e;
                const int ng = n0 + wn * 64 + j * 16 + lr;
                float v = acc[i][j][e];
                if (MODE == 1) {
                    ((short*)O0)[(long)z * oBatch + (long)mg * ldo + ng] = f2bits(v);
                } else {
                    ((float*)O0)[(long)mg * ldo + ng] = v + b0[ng];
                }
            }
        }
    }
}

// ---------------------------------------------------------------------------
// p2c_fused: per (k-octant of 64, bh) block (512 threads, 8 waves).
// XCD-chunked grid: each XCD owns 16 complete bh -> c2p/posQ/K L2-local.
//   strip[p][kk] = sum_d posQ[p][d] * K[k0+kk][d]   (512 x 64, MFMA)
//   then combined bias plane in fragment-packed layout.
// ---------------------------------------------------------------------------
__global__ __launch_bounds__(512, 2)
void p2c_fused(const short* __restrict__ posQ, const short* __restrict__ K,
               const short* __restrict__ c2pf, const int* __restrict__ ftab,
               short* __restrict__ Bias)
{
    __shared__ __align__(16) short As[512 * 64];   // posQ staged; later strip
    __shared__ __align__(16) short Bs[64 * 64];    // K slice
    __shared__ short ft[1024];
    const int lin = blockIdx.x;
    const int swz = (lin & 7) * 128 + (lin >> 3);
    const int bh = swz >> 3, ko = swz & 7;
    const int k0 = ko * 64;
    const int t = threadIdx.x, l = t & 63, w = t >> 6;
    const int lr = l & 15, lg = l >> 4;
    const short* Ab = posQ + (long)bh * SEQ * HEAD_DIM;
    const short* Kb = K + (long)bh * SEQ * HEAD_DIM;
    const short* c2pb = c2pf + (long)bh * SEQ * POSN;

    for (int i = t; i < 1024; i += 512) ft[i] = (short)((i < 1023) ? ftab[i] : 0);

#pragma unroll
    for (int j = 0; j < 8; j++) {
        const int c = j * 512 + t;            // 0..4095 (lane-linear dest)
        const int row = c >> 3, pc = c & 7;
        const int cc = pc ^ (row & 7);
        GLDS16(Ab + (long)row * HEAD_DIM + cc * 8, As + c * 8);
    }
    {
        const int c = t;                      // 0..511
        const int row = c >> 3, pc = c & 7;
        const int cc = pc ^ (row & 7);
        GLDS16(Kb + (long)(k0 + row) * HEAD_DIM + cc * 8, Bs + c * 8);
    }
    __syncthreads();

    floatx4 acc[4][4];
#pragma unroll
    for (int i = 0; i < 4; i++)
#pragma unroll
        for (int j = 0; j < 4; j++) acc[i][j] = (floatx4){0.f, 0.f, 0.f, 0.f};
#pragma unroll
    for (int ks = 0; ks < 2; ks++) {
        short8 af[4], bfr[4];
#pragma unroll
        for (int i = 0; i < 4; i++) {
            const int mr = w * 64 + i * 16 + lr;
            af[i] = *(const short8*)((char*)As + mr * 128 + (((ks * 4 + lg) ^ (mr & 7)) * 16));
            const int nr = i * 16 + lr;
            bfr[i] = *(const short8*)((char*)Bs + nr * 128 + (((ks * 4 + lg) ^ (nr & 7)) * 16));
        }
#pragma unroll
        for (int i = 0; i < 4; i++)
#pragma unroll
            for (int j = 0; j < 4; j++)
                acc[i][j] = __builtin_amdgcn_mfma_f32_16x16x32_bf16(af[i], bfr[j], acc[i][j], 0, 0, 0);
    }
    __syncthreads();   // all As/Bs reads done -> reuse As as strip

#pragma unroll
    for (int i = 0; i < 4; i++)
#pragma unroll
        for (int j = 0; j < 4; j++)
#pragma unroll
            for (int e = 0; e < 4; e++) {
                const int p = w * 64 + i * 16 + lg * 4 + e;
                const int kk = j * 16 + lr;
                As[p * 64 + (kk ^ (lg << 4))] = f2bits(acc[i][j][e]);
            }
    __syncthreads();

    // combined-bias build: 4096 tasks, fragment-packed stores
    short* Bb = Bias + (long)bh * SEQ * SEQ;    // [16 qt][16384]
#pragma unroll
    for (int j = 0; j < 8; j++) {
        const int task = j * 512 + t;
        const int qt = task >> 8;              // 0..15
        const int kl = (task >> 2) & 63;       // 0..63
        const int rc = task & 3;               // 0..3
        const int k  = k0 + kl;
        short8 v;
#pragma unroll
        for (int i = 0; i < 8; i++) {
            const int q  = qt * 32 + rc * 8 + i;
            const int fk = (int)ft[q - k + 511];
            const float sv = bits2f(As[fk * 64 + (kl ^ (((fk >> 2) & 3) << 4))]);
            const float cv = bits2f(c2pb[(long)q * POSN + fk]);
            v[i] = f2bits(sv + cv);
        }
        short* Bq = Bb + qt * 16384;
        const int mt  = rc >> 1;
        const int lg0 = (rc * 2) & 3;
        const int pb  = (((mt * 4 + (k >> 7)) * 8 + ((k >> 4) & 7)) * 64
                         + (lg0 * 16 + (k & 15))) * 4;
        *(short4_t*)(Bq + pb)      = (short4_t){v[0], v[1], v[2], v[3]};
        *(short4_t*)(Bq + pb + 64) = (short4_t){v[4], v[5], v[6], v[7]};
    }
}

// ---------------------------------------------------------------------------
// Fused attention per (b,h, 32-row q-tile). 4 waves, ONE barrier.
//   Fragment-packed bias -> 16 coalesced short4 loads; no-max softmax;
//   fused exp+sum+P-write; setprio around MFMA clusters.
// LDS 32.5 KB -> 4 blocks/CU.
// ---------------------------------------------------------------------------
__global__ __launch_bounds__(256, 4)
void attn_fused(const short* __restrict__ Q, const short* __restrict__ K,
                const short* __restrict__ Vt, const short* __restrict__ Bias,
                short* __restrict__ attnO)
{
    __shared__ __align__(16) short PS[32 * 512];   // swizzled P tile
    __shared__ float red[4][32];                   // wave-partial row sums

    const int lin  = blockIdx.x;
    const int lin2 = (lin & 7) * 256 + (lin >> 3);
    const int bh = lin2 >> 4, qt = lin2 & 15;
    const int q0 = qt * 32;
    const int t = threadIdx.x, l = t & 63, w = t >> 6;
    const int lr = l & 15, lg = l >> 4;
    const long pbase = (long)bh * SEQ * HEAD_DIM;
    const short* Qb  = Q  + pbase;
    const short* Kb  = K  + pbase;
    const short* Vtb = Vt + pbase;
    const short* Bb  = Bias + ((long)bh * 16 + qt) * (512 * 32);

    short4_t bfrag[2][8];
#pragma unroll
    for (int mt = 0; mt < 2; mt++)
#pragma unroll
        for (int nt = 0; nt < 8; nt++)
            bfrag[mt][nt] = *(const short4_t*)(Bb + ((((mt * 4 + w) * 8 + nt) * 64 + l) << 2));

    short8 aq[2][2];
#pragma unroll
    for (int mt = 0; mt < 2; mt++)
#pragma unroll
        for (int ks = 0; ks < 2; ks++)
            aq[mt][ks] = *(const short8*)(Qb + (q0 + mt * 16 + lr) * 64 + ks * 32 + lg * 8);

    floatx4 acc[2][8];
#pragma unroll
    for (int mt = 0; mt < 2; mt++)
#pragma unroll
        for (int nt = 0; nt < 8; nt++) acc[mt][nt] = (floatx4){0.f, 0.f, 0.f, 0.f};

    __builtin_amdgcn_s_setprio(1);
#pragma unroll
    for (int nt = 0; nt < 8; nt++) {
        const int kr = w * 128 + nt * 16 + lr;
        short8 kb0 = *(const short8*)(Kb + kr * 64 + lg * 8);
        short8 kb1 = *(const short8*)(Kb + kr * 64 + 32 + lg * 8);
#pragma unroll
        for (int mt = 0; mt < 2; mt++) {
            acc[mt][nt] = __builtin_amdgcn_mfma_f32_16x16x32_bf16(aq[mt][0], kb0, acc[mt][nt], 0, 0, 0);
            acc[mt][nt] = __builtin_amdgcn_mfma_f32_16x16x32_bf16(aq[mt][1], kb1, acc[mt][nt], 0, 0, 0);
        }
    }
    __builtin_amdgcn_s_setprio(0);

#pragma unroll
    for (int mt = 0; mt < 2; mt++)
#pragma unroll
        for (int e = 0; e < 4; e++) {
            const int r = mt * 16 + lg * 4 + e;
            float s = 0.f;
#pragma unroll
            for (int nt = 0; nt < 8; nt++) {
                float p = __expf((acc[mt][nt][e] + bits2f(bfrag[mt][nt][e])) * SCALE_F);
                acc[mt][nt][e] = p;
                s += p;
            }
            s += __shfl_xor(s, 1); s += __shfl_xor(s, 2);
            s += __shfl_xor(s, 4); s += __shfl_xor(s, 8);
            red[w][r] = s;
#pragma unroll
            for (int nt = 0; nt < 8; nt++) {
                const int kcol = w * 128 + nt * 16 + lr;
                int byte = r * 1024 + kcol * 2;
                byte ^= (r & 7) << 4;
                *(short*)((char*)PS + byte) = f2bits(acc[mt][nt][e]);
            }
        }
    __syncthreads();   // P tile + partial sums visible

    floatx4 accO[2];
    accO[0] = (floatx4){0.f, 0.f, 0.f, 0.f};
    accO[1] = (floatx4){0.f, 0.f, 0.f, 0.f};
    __builtin_amdgcn_s_setprio(1);
#pragma unroll
    for (int ks = 0; ks < 16; ks++) {
        short8 vb = *(const short8*)(Vtb + (long)(w * 16 + lr) * SEQ + ks * 32 + lg * 8);
#pragma unroll
        for (int mt = 0; mt < 2; mt++) {
            const int qr = mt * 16 + lr;
            int byte = qr * 1024 + (ks * 32 + lg * 8) * 2;
            byte ^= (qr & 7) << 4;
            short8 pa = *(const short8*)((char*)PS + byte);
            accO[mt] = __builtin_amdgcn_mfma_f32_16x16x32_bf16(pa, vb, accO[mt], 0, 0, 0);
        }
    }
    __builtin_amdgcn_s_setprio(0);

    const int b = bh >> 4, h = bh & 15;
#pragma unroll
    for (int mt = 0; mt < 2; mt++)
#pragma unroll
        for (int e = 0; e < 4; e++) {
            const int r = mt * 16 + lg * 4 + e;
            const float rs = red[0][r] + red[1][r] + red[2][r] + red[3][r];
            const float v = accO[mt][e] / rs;
            attnO[((long)(b * SEQ + q0 + r)) * HIDDEN + h * HEAD_DIM + w * 16 + lr] = f2bits(v);
        }
}

// ---------------------------------------------------------------------------
extern "C" void kernel_launch(void* const* d_in, const int* in_sizes, int n_in,
                              void* d_out, int out_size, void* d_ws, size_t ws_size,
                              hipStream_t stream)
{
    const float* inputs = (const float*)d_in[0];
    const float* rel    = (const float*)d_in[1];
    const float* Wq     = (const float*)d_in[2];
    const float* bq     = (const float*)d_in[3];
    const float* Wk     = (const float*)d_in[4];
    const float* bk     = (const float*)d_in[5];
    const float* Wv     = (const float*)d_in[6];
    const float* bv     = (const float*)d_in[7];
    const float* Wo     = (const float*)d_in[8];
    const float* bo     = (const float*)d_in[9];
    float* out = (float*)d_out;

    char* ws = (char*)d_ws;
    size_t off = 0;
    auto alloc = [&](size_t bytes) -> char* {
        char* p = ws + off;
        off += (bytes + 255) & ~(size_t)255;
        return p;
    };
    short* inA   = (short*)alloc(4194304ull * 2);
    short* inRel = (short*)alloc(4194304ull * 2);
    short* WqT   = (short*)alloc(1048576ull * 2);   // WqT/WkT/WvT contiguous ->
    short* WkT   = (short*)alloc(1048576ull * 2);   // concat B for fused GEMMs
    short* WvT   = (short*)alloc(1048576ull * 2);
    short* WoT   = (short*)alloc(1048576ull * 2);
    short* Qw    = (short*)alloc(4194304ull * 2);
    short* Kw    = (short*)alloc(4194304ull * 2);
    short* Vtw   = (short*)alloc(4194304ull * 2);
    short* posQw = (short*)alloc(4194304ull * 2);
    short* posKw = (short*)alloc(4194304ull * 2);
    short* c2pW  = (short*)alloc(33554432ull * 2);
    short* BW    = (short*)alloc(33554432ull * 2);  // combined pos-bias plane
    short* attnW = (short*)alloc(4194304ull * 2);
    int*   ftabW = (int*)alloc(4096);
    // total ws: ~209.7 MB (known-safe footprint)

    // prep (conv + wtrans + ftab in one launch)
    prep_all<<<5124, 256, 0, stream>>>(inputs, rel, inA, inRel,
                                       Wq, Wk, Wv, Wo, WqT, WkT, WvT, WoT, ftabW);

    // merged projections (BK=64 2-stage variant — best for K=1024)
    gemm_nt<6><<<dim3(32, 40), 256, 0, stream>>>(inA, 0, 1024, WqT, 0, 1024,
                                                 Qw, Kw, Vtw, 0, 0, bq, bk, bv, 1024,
                                                 inRel, posQw, posKw);

    // c2p score GEMM: c2p = Q @ posK^T  (3-stage variant — best occupancy)
    gemm_nt3<1><<<dim3(4, 4, 128), 256, 0, stream>>>(Qw, 32768, 64, posKw, 32768, 64,
                                                     c2pW, 262144, 512, nullptr, 64);

    // p2c strip GEMM + c2p gather + combine -> fragment-packed Bias
    // (XCD-chunked: each XCD owns 16 complete bh)
    p2c_fused<<<1024, 512, 0, stream>>>(posQw, Kw, c2pW, ftabW, BW);

    // fused scores+softmax+PV (q-tile 32, one barrier, no-max softmax)
    attn_fused<<<2048, 256, 0, stream>>>(Qw, Kw, Vtw, BW, attnW);

    // output projection (3-stage variant)
    gemm_nt3<2><<<dim3(32, 8), 256, 0, stream>>>(attnW, 0, 1024, WoT, 0, 1024,
                                                 out, 0, 1024, bo, 1024);
}